// Round 3
// baseline (291.644 us; speedup 1.0000x reference)
//
#include <hip/hip_runtime.h>
#include <hip/hip_bf16.h>
#include <hip/hip_fp16.h>

typedef unsigned short u16;
typedef _Float16 f16;
typedef f16 f16x8 __attribute__((ext_vector_type(8)));
typedef f16 f16x4 __attribute__((ext_vector_type(4)));
typedef float f32x4 __attribute__((ext_vector_type(4)));

#define DEVI static __device__ __forceinline__

constexpr int Bc = 2, Lc = 1024, Dc = 1024, Hc = 16, DKc = 64, Rc = 130;
constexpr float SCALE = 0.07216878364870323f; // 1/sqrt(64*3)

// ---------------------------------------------------------------------------
// NT GEMM: C[2048,1024] = A[2048,1024](f32) * W[1024,1024](f32)^T + bias(f32).
// Internally f16 MFMA. MODE 0: out f16 [B,H,L,DK] (q/k). MODE 1: out f16
// [B,H,DK,L] (v transposed). MODE 2: outf f32 [rows,D] (final output).
// Tile 128x64, BK=32, 4 waves (2x2), each wave 64x32 = 4x2 frags 16x16.
// ---------------------------------------------------------------------------
template <int MODE>
__global__ __launch_bounds__(256) void gemm_nt(const float* __restrict__ A,
                                               const float* __restrict__ W,
                                               const float* __restrict__ bias,
                                               f16* __restrict__ out,
                                               float* __restrict__ outf) {
    constexpr int K = 1024;
    __shared__ __align__(16) f16 As[128][40];
    __shared__ __align__(16) f16 Bs[64][40];
    const int tid = threadIdx.x, lane = tid & 63, w = tid >> 6;
    const int wm = w >> 1, wn = w & 1;
    const int m0 = blockIdx.y * 128, n0 = blockIdx.x * 64;

    f32x4 acc[4][2];
#pragma unroll
    for (int i = 0; i < 4; ++i)
#pragma unroll
        for (int j = 0; j < 2; ++j) acc[i][j] = (f32x4){0.f, 0.f, 0.f, 0.f};

    for (int k0 = 0; k0 < K; k0 += 32) {
#pragma unroll
        for (int rep = 0; rep < 4; ++rep) {  // A tile 128x32 f32 -> f16
            int id = tid + rep * 256;
            int row = id >> 3, c = (id & 7) * 4;
            float4 v = *(const float4*)&A[(size_t)(m0 + row) * K + k0 + c];
            f16x4 pk = {(f16)v.x, (f16)v.y, (f16)v.z, (f16)v.w};
            *(f16x4*)&As[row][c] = pk;
        }
#pragma unroll
        for (int rep = 0; rep < 2; ++rep) {  // W tile 64x32 f32 -> f16
            int id = tid + rep * 256;
            int row = id >> 3, c = (id & 7) * 4;
            float4 v = *(const float4*)&W[(size_t)(n0 + row) * K + k0 + c];
            f16x4 pk = {(f16)v.x, (f16)v.y, (f16)v.z, (f16)v.w};
            *(f16x4*)&Bs[row][c] = pk;
        }
        __syncthreads();
        f16x8 a[4], bb[2];
#pragma unroll
        for (int mf = 0; mf < 4; ++mf)
            a[mf] = *(const f16x8*)&As[wm * 64 + mf * 16 + (lane & 15)][(lane >> 4) * 8];
#pragma unroll
        for (int nf = 0; nf < 2; ++nf)
            bb[nf] = *(const f16x8*)&Bs[wn * 32 + nf * 16 + (lane & 15)][(lane >> 4) * 8];
#pragma unroll
        for (int mf = 0; mf < 4; ++mf)
#pragma unroll
            for (int nf = 0; nf < 2; ++nf)
                acc[mf][nf] = __builtin_amdgcn_mfma_f32_16x16x32_f16(a[mf], bb[nf], acc[mf][nf], 0, 0, 0);
        __syncthreads();
    }

#pragma unroll
    for (int mf = 0; mf < 4; ++mf)
#pragma unroll
        for (int nf = 0; nf < 2; ++nf) {
            int rowb = m0 + wm * 64 + mf * 16 + (lane >> 4) * 4;
            int col = n0 + wn * 32 + nf * 16 + (lane & 15);
            float bv = bias[col];
            if (MODE == 1) {
                int b = rowb >> 10, i = rowb & (Lc - 1), h = col >> 6, d = col & 63;
                f16x4 pk = {(f16)(acc[mf][nf][0] + bv), (f16)(acc[mf][nf][1] + bv),
                            (f16)(acc[mf][nf][2] + bv), (f16)(acc[mf][nf][3] + bv)};
                *(f16x4*)&out[(((size_t)(b * Hc + h)) * DKc + d) * Lc + i] = pk;
            } else {
#pragma unroll
                for (int rg = 0; rg < 4; ++rg) {
                    int row = rowb + rg;
                    float v = acc[mf][nf][rg] + bv;
                    if (MODE == 0) {
                        int b = row >> 10, i = row & (Lc - 1), h = col >> 6, d = col & 63;
                        out[(((size_t)(b * Hc + h)) * Lc + i) * DKc + d] = (f16)v;
                    } else {
                        outf[(size_t)row * Dc + col] = v;
                    }
                }
            }
        }
}

// ---------------------------------------------------------------------------
// rel tables (f16 out): outT[(bh*R+r)*L+i] = SCALE * dot(rowmat[bh,i,:], relmat[h,r,:])
// rowmat: [B,H,L,DK] f16 (q or k); relmat: [H,R,DK] f32.
// grid: (L/256, B*H), 256 threads; each thread owns one row i.
// ---------------------------------------------------------------------------
__global__ __launch_bounds__(256) void rel_gemm(const f16* __restrict__ rowmat,
                                                const float* __restrict__ relmat,
                                                f16* __restrict__ outT) {
    __shared__ float rel_lds[Rc * DKc];
    const int tid = threadIdx.x;
    const int bh = blockIdx.y, h = bh & (Hc - 1);
    for (int e = tid; e < Rc * DKc; e += 256)
        rel_lds[e] = relmat[(size_t)h * Rc * DKc + e] * SCALE;
    __syncthreads();

    const int i = blockIdx.x * 256 + tid;
    float qf[64];
    const f16* rp = &rowmat[((size_t)bh * Lc + i) * DKc];
#pragma unroll
    for (int c = 0; c < 8; ++c) {
        f16x8 v = *(const f16x8*)&rp[c * 8];
#pragma unroll
        for (int e = 0; e < 8; ++e) qf[c * 8 + e] = (float)v[e];
    }
    for (int r = 0; r < Rc; ++r) {
        const float* rl = &rel_lds[r * DKc];
        float a0 = 0.f, a1 = 0.f, a2 = 0.f, a3 = 0.f;
#pragma unroll
        for (int c = 0; c < DKc; c += 4) {
            a0 += qf[c] * rl[c];
            a1 += qf[c + 1] * rl[c + 1];
            a2 += qf[c + 2] * rl[c + 2];
            a3 += qf[c + 3] * rl[c + 3];
        }
        outT[((size_t)bh * Rc + r) * Lc + i] = (f16)((a0 + a1) + (a2 + a3));
    }
}

// ---------------------------------------------------------------------------
// Fused attention. grid: (L/64, B*H); 256 threads = 4 waves, wave w owns rows
// i0 + w*16 .. +16. Loop over 32-wide j-tiles with online softmax.
// scores = c2c*SCALE + p2c[r1=pos[i,j]][j] + c2pT[r2=pos[j,i]][i] + mask
// ---------------------------------------------------------------------------
__global__ __launch_bounds__(256) void attn(const f16* __restrict__ q,
                                            const f16* __restrict__ k,
                                            const f16* __restrict__ vt,
                                            const f16* __restrict__ c2pT,
                                            const f16* __restrict__ p2c,
                                            const int* __restrict__ pos,
                                            const int* __restrict__ mask,
                                            float* __restrict__ ctx) {
    __shared__ __align__(16) f16 c2p_lds[Rc][72];  // [r][i_local]
    __shared__ __align__(16) f16 p2c_lds[Rc][40];  // [r][j_local]
    __shared__ __align__(16) f16 Ks[32][72];       // [j][d]
    __shared__ __align__(16) f16 Pl[4][16][40];    // per-wave [i][j]
    __shared__ __align__(16) f16 Vs[64][40];       // [d][j]
    __shared__ __align__(16) unsigned char posJI[32][72];
    __shared__ float madd[32];

    const int tid = threadIdx.x, lane = tid & 63, w = tid >> 6;
    const int bh = blockIdx.y, b = bh >> 4, h = bh & 15;
    const int i0 = blockIdx.x * 64;
    const size_t bhL = (size_t)bh * Lc;
    const size_t bhR = (size_t)bh * Rc;

    // stage c2p rows for this i-tile (reused across all j-tiles): 130x64 f16
    for (int cch = tid; cch < Rc * 8; cch += 256) {
        int r = cch >> 3, cc = (cch & 7) * 8;
        *(f16x8*)&c2p_lds[r][cc] = *(const f16x8*)&c2pT[(bhR + r) * Lc + i0 + cc];
    }

    // Q fragments (rows i0 + w*16 + (lane&15))
    f16x8 qa[2];
    {
        const f16* qp = &q[(bhL + i0 + w * 16 + (lane & 15)) * DKc + (lane >> 4) * 8];
        qa[0] = *(const f16x8*)qp;
        qa[1] = *(const f16x8*)(qp + 32);
    }

    float mrun[4], lrun[4];
    f32x4 oacc[4];
#pragma unroll
    for (int r = 0; r < 4; ++r) {
        mrun[r] = -1e30f;
        lrun[r] = 0.f;
        oacc[r] = (f32x4){0.f, 0.f, 0.f, 0.f};
    }
    const int il_base = w * 16 + (lane >> 4) * 4;
    const int jl = lane & 15;

    for (int jt = 0; jt < Lc / 32; ++jt) {
        const int j0 = jt * 32;
        __syncthreads();  // previous tile fully consumed (also covers c2p stage)
        {   // K tile [32][64]
            int jj = tid >> 3, c = (tid & 7) * 8;
            *(f16x8*)&Ks[jj][c] = *(const f16x8*)&k[(bhL + j0 + jj) * DKc + c];
        }
        {   // Vt tile [64][32]
            int dd = tid >> 2, c = (tid & 3) * 8;
            *(f16x8*)&Vs[dd][c] = *(const f16x8*)&vt[((size_t)bh * DKc + dd) * Lc + j0 + c];
        }
        {   // pos[j,i] tile as uchar
            int jj = tid >> 3, ii = (tid & 7) * 8;
            const int* pp = &pos[(bhL + j0 + jj) * Lc + i0 + ii];
            int4 pa4 = *(const int4*)pp;
            int4 pb4 = *(const int4*)(pp + 4);
            unsigned lo = (unsigned)(pa4.x & 255) | ((unsigned)(pa4.y & 255) << 8) |
                          ((unsigned)(pa4.z & 255) << 16) | ((unsigned)(pa4.w & 255) << 24);
            unsigned hi = (unsigned)(pb4.x & 255) | ((unsigned)(pb4.y & 255) << 8) |
                          ((unsigned)(pb4.z & 255) << 16) | ((unsigned)(pb4.w & 255) << 24);
            *(unsigned*)&posJI[jj][ii] = lo;
            *(unsigned*)&posJI[jj][ii + 4] = hi;
        }
        for (int cch = tid; cch < Rc * 4; cch += 256) {  // p2c tile [130][32] f16
            int r = cch >> 2, cc = (cch & 3) * 8;
            *(f16x8*)&p2c_lds[r][cc] = *(const f16x8*)&p2c[(bhR + r) * Lc + j0 + cc];
        }
        if (tid < 32) madd[tid] = mask[b * Lc + j0 + tid] ? -1e9f : 0.f;
        __syncthreads();

        // QK^T
        f32x4 s[2];
        s[0] = (f32x4){0.f, 0.f, 0.f, 0.f};
        s[1] = (f32x4){0.f, 0.f, 0.f, 0.f};
#pragma unroll
        for (int jf = 0; jf < 2; ++jf)
#pragma unroll
            for (int ks = 0; ks < 2; ++ks) {
                f16x8 kb = *(const f16x8*)&Ks[jf * 16 + jl][ks * 32 + (lane >> 4) * 8];
                s[jf] = __builtin_amdgcn_mfma_f32_16x16x32_f16(qa[ks], kb, s[jf], 0, 0, 0);
            }

        // score assembly with gathers
        float sv[2][4];
#pragma unroll
        for (int jf = 0; jf < 2; ++jf) {
            int jcol = jf * 16 + jl;
#pragma unroll
            for (int rg = 0; rg < 4; ++rg) {
                int il = il_base + rg;
                int r1 = pos[(bhL + i0 + il) * Lc + j0 + jcol];
                int r2 = posJI[jcol][il];
                sv[jf][rg] = s[jf][rg] * SCALE + (float)p2c_lds[r1][jcol] + (float)c2p_lds[r2][il] + madd[jcol];
            }
        }

        // online softmax (rows live in 16-lane groups; reduce over lane&15)
        float alpha[4];
#pragma unroll
        for (int rg = 0; rg < 4; ++rg) {
            float tm = fmaxf(sv[0][rg], sv[1][rg]);
#pragma unroll
            for (int d = 1; d < 16; d <<= 1) tm = fmaxf(tm, __shfl_xor(tm, d, 64));
            float mnew = fmaxf(mrun[rg], tm);
            alpha[rg] = __expf(mrun[rg] - mnew);
            float rs = 0.f;
#pragma unroll
            for (int jf = 0; jf < 2; ++jf) {
                sv[jf][rg] = __expf(sv[jf][rg] - mnew);
                rs += sv[jf][rg];
            }
#pragma unroll
            for (int d = 1; d < 16; d <<= 1) rs += __shfl_xor(rs, d, 64);
            lrun[rg] = lrun[rg] * alpha[rg] + rs;
            mrun[rg] = mnew;
        }
#pragma unroll
        for (int df = 0; df < 4; ++df)
#pragma unroll
            for (int rg = 0; rg < 4; ++rg) oacc[df][rg] *= alpha[rg];

        // write P (wave-private buffer; same-wave LDS ops are ordered)
#pragma unroll
        for (int jf = 0; jf < 2; ++jf)
#pragma unroll
            for (int rg = 0; rg < 4; ++rg)
                Pl[w][(lane >> 4) * 4 + rg][jf * 16 + jl] = (f16)sv[jf][rg];

        // PV (A = P rows, B = Vt rows; K=32 = this j-tile)
        f16x8 pa = *(const f16x8*)&Pl[w][lane & 15][(lane >> 4) * 8];
#pragma unroll
        for (int df = 0; df < 4; ++df) {
            f16x8 vb = *(const f16x8*)&Vs[df * 16 + (lane & 15)][(lane >> 4) * 8];
            oacc[df] = __builtin_amdgcn_mfma_f32_16x16x32_f16(pa, vb, oacc[df], 0, 0, 0);
        }
    }

    // write ctx f32 [B, L, H, DK] (== [B, L, D])
#pragma unroll
    for (int df = 0; df < 4; ++df)
#pragma unroll
        for (int rg = 0; rg < 4; ++rg) {
            int i = i0 + il_base + rg;
            int d = df * 16 + (lane & 15);
            ctx[((size_t)(b * Lc + i) * Hc + h) * DKc + d] = oacc[df][rg] / lrun[rg];
        }
}

// ---------------------------------------------------------------------------
extern "C" void kernel_launch(void* const* d_in, const int* in_sizes, int n_in,
                              void* d_out, int out_size, void* d_ws, size_t ws_size,
                              hipStream_t stream) {
    const float* hid = (const float*)d_in[0];
    const float* rel_q = (const float*)d_in[1];
    const float* rel_k = (const float*)d_in[2];
    const float* Wq = (const float*)d_in[3];
    const float* bq = (const float*)d_in[4];
    const float* Wk = (const float*)d_in[5];
    const float* bk = (const float*)d_in[6];
    const float* Wv = (const float*)d_in[7];
    const float* bv = (const float*)d_in[8];
    const float* Wo = (const float*)d_in[9];
    const float* bo = (const float*)d_in[10];
    const int* pos = (const int*)d_in[11];
    const int* mask = (const int*)d_in[12];

    char* ws = (char*)d_ws;
    size_t off = 0;
    auto alloc = [&](size_t bytes) {
        void* p = ws + off;
        off += (bytes + 255) & ~(size_t)255;
        return p;
    };
    f16* qw = (f16*)alloc((size_t)Bc * Hc * Lc * DKc * 2);    // 4 MB
    f16* kw = (f16*)alloc((size_t)Bc * Hc * Lc * DKc * 2);    // 4 MB
    f16* vtw = (f16*)alloc((size_t)Bc * Hc * Lc * DKc * 2);   // 4 MB
    float* ctxf = (float*)alloc((size_t)Bc * Lc * Dc * 4);    // 8 MB
    f16* c2pTw = (f16*)alloc((size_t)Bc * Hc * Rc * Lc * 2);  // 8.5 MB
    f16* p2cw = (f16*)alloc((size_t)Bc * Hc * Rc * Lc * 2);   // 8.5 MB

    // Diagnostic guard: if scratch doesn't fit, do nothing -> absmax == max|ref|
    // distinguishes "ws too small" from dtype/logic bugs.
    if (off > ws_size) return;

    gemm_nt<0><<<dim3(16, 16), 256, 0, stream>>>(hid, Wq, bq, qw, nullptr);
    gemm_nt<0><<<dim3(16, 16), 256, 0, stream>>>(hid, Wk, bk, kw, nullptr);
    gemm_nt<1><<<dim3(16, 16), 256, 0, stream>>>(hid, Wv, bv, vtw, nullptr);
    rel_gemm<<<dim3(4, 32), 256, 0, stream>>>(qw, rel_k, c2pTw);
    rel_gemm<<<dim3(4, 32), 256, 0, stream>>>(kw, rel_q, p2cw);
    attn<<<dim3(16, 32), 256, 0, stream>>>(qw, kw, vtw, c2pTw, p2cw, pos, mask, ctxf);
    gemm_nt<2><<<dim3(16, 16), 256, 0, stream>>>(ctxf, Wo, bo, nullptr, (float*)d_out);
}